// Round 5
// baseline (611.132 us; speedup 1.0000x reference)
//
#include <hip/hip_runtime.h>
#include <math.h>

// Problem constants
#define B_ 8
#define C_ 256
#define H_ 56
#define W_ 56
#define N_ 3136  // 56*56 = 49*64

typedef __attribute__((ext_vector_type(8))) short short8;
typedef __attribute__((ext_vector_type(4))) float f32x4;
typedef __attribute__((ext_vector_type(16))) float f32x16;
typedef __attribute__((ext_vector_type(4))) unsigned short u16x4;
#define MFMA16(A, Bf, Cf) __builtin_amdgcn_mfma_f32_16x16x32_bf16((A), (Bf), (Cf), 0, 0, 0)
#define MFMA32(A, Bf, Cf) __builtin_amdgcn_mfma_f32_32x32x16_bf16((A), (Bf), (Cf), 0, 0, 0)

// -------------------- workspace layout (ushort units) --------------------
#define XT_ELEMS (B_*58*64*256)           // 7,602,176
#define A_ELEMS  (320*2304)               // 737,280
#define AHI_OFF  (2*XT_ELEMS)
#define ALO_OFF  (AHI_OFF + A_ELEMS)
#define QKT_HI_OFF (ALO_OFF + A_ELEMS)
#define QKT_ELEMS  (B_*N_*64)             // 1,605,632
#define QKT_LO_OFF (QKT_HI_OFF + QKT_ELEMS)
#define VBF_OFF    (QKT_LO_OFF + QKT_ELEMS)
#define VBF_ELEMS  (B_*C_*N_)             // 6,422,528

// LDS swizzle for conv B-slabs: chunk (r,col,c8) -> uint4 index
#define SWZ(r, col, c8) ((((r)*64 + (col))*4) + ((c8) ^ ((col) & 3)))

__device__ inline unsigned short f2bf(float f) {
    unsigned u = __float_as_uint(f);
    unsigned r = (u + 0x7fffu + ((u >> 16) & 1u)) >> 16;   // RNE
    return (unsigned short)r;
}
__device__ inline float bf2f(unsigned short h) {
    return __uint_as_float(((unsigned)h) << 16);
}

// ---------------------------------------------------------------------------
// Kernel 0: zero the padded x regions.
// ---------------------------------------------------------------------------
__global__ __launch_bounds__(256) void zero_pads(uint4* __restrict__ p, int n16)
{
    const int stride = gridDim.x * 256;
    for (int i = blockIdx.x * 256 + threadIdx.x; i < n16; i += stride)
        p[i] = make_uint4(0, 0, 0, 0);
}

// ---------------------------------------------------------------------------
// Kernel 1a: x (fp32 NCHW) -> padded pixel-major bf16 hi/lo.
// ---------------------------------------------------------------------------
__global__ __launch_bounds__(256) void prep_x(
    const float* __restrict__ x,
    unsigned short* __restrict__ xhi, unsigned short* __restrict__ xlo)
{
    __shared__ float xs[64][57];
    const int cc = blockIdx.x, y = blockIdx.y, b = blockIdx.z;
    const int t = threadIdx.x;
    const int c0 = cc * 64;
    for (int idx = t; idx < 64 * 56; idx += 256) {
        const int ch = idx / 56, xc = idx - ch * 56;
        xs[ch][xc] = x[((size_t)(b*C_ + c0 + ch)*H_ + y)*W_ + xc];
    }
    __syncthreads();
    for (int idx = t; idx < 56 * 32; idx += 256) {
        const int xc = idx >> 5, chp = idx & 31;
        const float v0 = xs[2*chp][xc], v1 = xs[2*chp + 1][xc];
        const unsigned short h0 = f2bf(v0), h1 = f2bf(v1);
        const unsigned short l0 = f2bf(v0 - bf2f(h0));
        const unsigned short l1 = f2bf(v1 - bf2f(h1));
        const size_t o = ((size_t)(b*58 + y + 1) * 64 + (xc + 1)) * 256 + c0 + 2*chp;
        *(unsigned*)(xhi + o) = (unsigned)h0 | ((unsigned)h1 << 16);
        *(unsigned*)(xlo + o) = (unsigned)l0 | ((unsigned)l1 << 16);
    }
}

// ---------------------------------------------------------------------------
// Kernel 1b: weights -> A_hi/A_lo [320][2304], k = s*256 + c.
// ---------------------------------------------------------------------------
__global__ __launch_bounds__(256) void prep_w(
    const float* __restrict__ wq, const float* __restrict__ wk,
    const float* __restrict__ wv,
    unsigned short* __restrict__ Ahi, unsigned short* __restrict__ Alo)
{
    const int g = blockIdx.x * 256 + threadIdx.x;
    if (g >= 320 * 2304) return;
    const int m = g / 2304, k = g - m * 2304;
    const int s = k >> 8, c = k & 255;
    float w;
    if (m < 32)      w = wq[((size_t)m*C_ + c)*9 + s];
    else if (m < 64) w = wk[((size_t)(m-32)*C_ + c)*9 + s];
    else             w = wv[((size_t)(m-64)*C_ + c)*9 + s];
    const unsigned short h = f2bf(w);
    Ahi[g] = h;
    Alo[g] = f2bf(w - bf2f(h));
}

// ---------------------------------------------------------------------------
// Kernel 2a: q/k conv (bf16x3). grid (b 8, yt 28), block 256 = 4 waves.
// ---------------------------------------------------------------------------
__global__ __launch_bounds__(256, 2) void conv_qk(
    const unsigned short* __restrict__ xhi, const unsigned short* __restrict__ xlo,
    const unsigned short* __restrict__ Ahi, const unsigned short* __restrict__ Alo,
    const float* __restrict__ bq, const float* __restrict__ bk,
    unsigned short* __restrict__ qkt_hi, unsigned short* __restrict__ qkt_lo)
{
    __shared__ uint4 sH[4*64*4];   // 16 KB
    __shared__ uint4 sL[4*64*4];   // 16 KB
    const int b = blockIdx.x, yt = blockIdx.y;
    const int y0 = yt * 2;
    const int t = threadIdx.x;
    const int w = t >> 6, L = t & 63;
    const int ln = L & 15, quad = L >> 4;
    const int wm = w & 1, wn = w >> 1;

    f32x4 acc[2][4];
#pragma unroll
    for (int mt = 0; mt < 2; mt++)
#pragma unroll
        for (int nt = 0; nt < 4; nt++) acc[mt][nt] = (f32x4)0.0f;

    uint4 ph[4], pl[4];
#pragma unroll
    for (int i = 0; i < 4; i++) {
        const int idx = t + i*256;
        const int r = idx >> 8, col = (idx >> 2) & 63, c8 = idx & 3;
        const size_t go = ((size_t)((b*58 + y0 + r)*64 + col))*256 + c8*8;
        ph[i] = *(const uint4*)(xhi + go);
        pl[i] = *(const uint4*)(xlo + go);
    }

    for (int cc = 0; cc < 8; cc++) {
        __syncthreads();
#pragma unroll
        for (int i = 0; i < 4; i++) {
            const int idx = t + i*256;
            const int r = idx >> 8, col = (idx >> 2) & 63, c8 = idx & 3;
            sH[SWZ(r, col, c8)] = ph[i];
            sL[SWZ(r, col, c8)] = pl[i];
        }
        __syncthreads();
        if (cc < 7) {
#pragma unroll
            for (int i = 0; i < 4; i++) {
                const int idx = t + i*256;
                const int r = idx >> 8, col = (idx >> 2) & 63, c8 = idx & 3;
                const size_t go = ((size_t)((b*58 + y0 + r)*64 + col))*256 + (cc+1)*32 + c8*8;
                ph[i] = *(const uint4*)(xhi + go);
                pl[i] = *(const uint4*)(xlo + go);
            }
        }
#pragma unroll
        for (int s = 0; s < 9; s++) {
            const int dy = s / 3 - 1, dx = s % 3 - 1;
            short8 ah[2], al[2];
#pragma unroll
            for (int mt = 0; mt < 2; mt++) {
                const size_t off = (size_t)(wm*32 + mt*16 + ln)*2304 + s*256 + cc*32 + quad*8;
                ah[mt] = *(const short8*)(Ahi + off);
                al[mt] = *(const short8*)(Alo + off);
            }
            const int r = wn + dy + 1;
            short8 bh[4], bl[4];
#pragma unroll
            for (int nt = 0; nt < 4; nt++) {
                const int col = nt*16 + ln + dx + 1;
                const int i4 = SWZ(r, col, quad);
                bh[nt] = *(const short8*)&sH[i4];
                bl[nt] = *(const short8*)&sL[i4];
            }
#pragma unroll
            for (int mt = 0; mt < 2; mt++)
#pragma unroll
                for (int nt = 0; nt < 4; nt++) {
                    acc[mt][nt] = MFMA16(ah[mt], bh[nt], acc[mt][nt]);
                    acc[mt][nt] = MFMA16(ah[mt], bl[nt], acc[mt][nt]);
                    acc[mt][nt] = MFMA16(al[mt], bh[nt], acc[mt][nt]);
                }
        }
    }

    const int y = y0 + wn;
#pragma unroll
    for (int nt = 0; nt < 4; nt++) {
        const int px = nt*16 + ln;
        if (px >= 56) continue;
        const int pix = y*56 + px;
#pragma unroll
        for (int mt = 0; mt < 2; mt++) {
            u16x4 hi4, lo4;
#pragma unroll
            for (int r = 0; r < 4; r++) {
                const int m = wm*32 + mt*16 + quad*4 + r;
                const float bias = (m < 32) ? bq[m] : bk[m - 32];
                const float val = acc[mt][nt][r] + bias;
                const unsigned short h = f2bf(val);
                hi4[r] = h;
                lo4[r] = f2bf(val - bf2f(h));
            }
            const size_t o = (size_t)(b*N_ + pix)*64 + wm*32 + mt*16 + quad*4;
            *(u16x4*)(qkt_hi + o) = hi4;
            *(u16x4*)(qkt_lo + o) = lo4;
        }
    }
}

// ---------------------------------------------------------------------------
// Kernel 2b: v conv (plain bf16). grid (b 8, yt 14, mg 2), block 512 = 8 waves.
// ---------------------------------------------------------------------------
__global__ __launch_bounds__(512, 2) void conv_v(
    const unsigned short* __restrict__ xhi,
    const unsigned short* __restrict__ Ahi,
    const float* __restrict__ bv,
    unsigned short* __restrict__ vbf)
{
    __shared__ uint4 sH[6*64*4];   // 24 KB
    const int b = blockIdx.x, yt = blockIdx.y, mg = blockIdx.z;
    const int y0 = yt * 4;
    const int t = threadIdx.x;
    const int w = t >> 6, L = t & 63;
    const int ln = L & 15, quad = L >> 4;
    const int wm = w & 1, wn = w >> 1;
    const int m0 = 64 + mg*128 + wm*64;

    f32x4 acc[4][4];
#pragma unroll
    for (int mt = 0; mt < 4; mt++)
#pragma unroll
        for (int nt = 0; nt < 4; nt++) acc[mt][nt] = (f32x4)0.0f;

    uint4 ph[3];
#pragma unroll
    for (int i = 0; i < 3; i++) {
        const int idx = t + i*512;
        const int r = idx >> 8, col = (idx >> 2) & 63, c8 = idx & 3;
        const size_t go = ((size_t)((b*58 + y0 + r)*64 + col))*256 + c8*8;
        ph[i] = *(const uint4*)(xhi + go);
    }

    for (int cc = 0; cc < 8; cc++) {
        __syncthreads();
#pragma unroll
        for (int i = 0; i < 3; i++) {
            const int idx = t + i*512;
            const int r = idx >> 8, col = (idx >> 2) & 63, c8 = idx & 3;
            sH[SWZ(r, col, c8)] = ph[i];
        }
        __syncthreads();
        if (cc < 7) {
#pragma unroll
            for (int i = 0; i < 3; i++) {
                const int idx = t + i*512;
                const int r = idx >> 8, col = (idx >> 2) & 63, c8 = idx & 3;
                const size_t go = ((size_t)((b*58 + y0 + r)*64 + col))*256 + (cc+1)*32 + c8*8;
                ph[i] = *(const uint4*)(xhi + go);
            }
        }
#pragma unroll
        for (int s = 0; s < 9; s++) {
            const int dy = s / 3 - 1, dx = s % 3 - 1;
            short8 a[4];
#pragma unroll
            for (int mt = 0; mt < 4; mt++) {
                const size_t off = (size_t)(m0 + mt*16 + ln)*2304 + s*256 + cc*32 + quad*8;
                a[mt] = *(const short8*)(Ahi + off);
            }
            const int r = wn + dy + 1;
            short8 bf[4];
#pragma unroll
            for (int nt = 0; nt < 4; nt++) {
                const int col = nt*16 + ln + dx + 1;
                bf[nt] = *(const short8*)&sH[SWZ(r, col, quad)];
            }
#pragma unroll
            for (int mt = 0; mt < 4; mt++)
#pragma unroll
                for (int nt = 0; nt < 4; nt++)
                    acc[mt][nt] = MFMA16(a[mt], bf[nt], acc[mt][nt]);
        }
    }

    const int y = y0 + wn;
#pragma unroll
    for (int nt = 0; nt < 4; nt++) {
        const int px = nt*16 + ln;
        if (px >= 56) continue;
        const int pix = y*56 + px;
#pragma unroll
        for (int mt = 0; mt < 4; mt++) {
#pragma unroll
            for (int r = 0; r < 4; r++) {
                const int c = mg*128 + wm*64 + mt*16 + quad*4 + r;
                vbf[(size_t)(b*C_ + c)*N_ + pix] = f2bf(acc[mt][nt][r] + bv[c]);
            }
        }
    }
}

// ---------------------------------------------------------------------------
// Kernel 3: fused flash attention. grid 784 (b = bid&7, r = bid>>3:
// it = r>>1, half = r&1 -> i0 = it*64 + half*32), block 256 = 4 waves.
// Wave w: row-group g = w&1 (16 i-rows), j-half jh = w>>1 (32 j per tile).
// Per jt: S (6 MFMA16 bf16x3) -> pair-wave max exchange -> P=exp(S-m) bf16
// -> LDS -> PV (8 MFMA32, V from L2) with per-i alpha rescale of O.
// 2 barriers/jt; single P buffer (writes in A->B window, reads in B->A).
// ---------------------------------------------------------------------------
__global__ __launch_bounds__(256) void attn_flash(
    const unsigned short* __restrict__ qkt_hi, const unsigned short* __restrict__ qkt_lo,
    const unsigned short* __restrict__ vbf,
    const float* __restrict__ x, const float* __restrict__ gptr,
    float* __restrict__ out)
{
    __shared__ unsigned short P[32*72];   // [i 32][j 64] stride 72, 4.5 KB
    __shared__ float pmax[4][16];
    __shared__ float alpha_lds[32];
    __shared__ float lpart[4][16];

    const int bid = blockIdx.x;
    const int b = bid & 7, rr = bid >> 3;
    const int it = rr >> 1, half = rr & 1;
    const int i0 = it*64 + half*32;
    const int t = threadIdx.x;
    const int w = t >> 6, L = t & 63;
    const int ln = L & 15, quad = L >> 4;
    const int l32 = L & 31, h32 = L >> 5;
    const int g = w & 1, jh = w >> 1;

    // q A-frags (rows i0 + g*16 + ln)
    const size_t qoff = (size_t)(b*N_ + i0 + g*16 + ln)*64 + quad*8;
    const short8 qh = *(const short8*)(qkt_hi + qoff);
    const short8 ql = *(const short8*)(qkt_lo + qoff);

    float m_run[4], l_run[4];
#pragma unroll
    for (int r = 0; r < 4; r++) { m_run[r] = -INFINITY; l_run[r] = 0.0f; }

    f32x16 O0 = (f32x16)0.0f, O1 = (f32x16)0.0f;
    const unsigned short* vbase = vbf + (size_t)b*C_*N_;

    for (int jt = 0; jt < 49; jt++) {
        // ---- S phase: S[16 i][32 j], bf16x3 ----
        f32x4 sacc[2];
#pragma unroll
        for (int u = 0; u < 2; u++) {
            const int tj = jh*2 + u;
            const size_t koff = (size_t)(b*N_ + jt*64 + tj*16 + ln)*64 + 32 + quad*8;
            const short8 kh = *(const short8*)(qkt_hi + koff);
            const short8 kl = *(const short8*)(qkt_lo + koff);
            f32x4 a = (f32x4)0.0f;
            a = MFMA16(qh, kh, a);
            a = MFMA16(qh, kl, a);
            a = MFMA16(ql, kh, a);
            sacc[u] = a;
        }
        // partial row max over this wave's 32 j (reduce over ln within quad)
        float pm[4];
#pragma unroll
        for (int r = 0; r < 4; r++) {
            float v = fmaxf(sacc[0][r], sacc[1][r]);
            v = fmaxf(v, __shfl_xor(v, 1));
            v = fmaxf(v, __shfl_xor(v, 2));
            v = fmaxf(v, __shfl_xor(v, 4));
            v = fmaxf(v, __shfl_xor(v, 8));
            pm[r] = v;
        }
        if (ln == 0) {
#pragma unroll
            for (int r = 0; r < 4; r++) pmax[w][quad*4 + r] = pm[r];
        }
        __syncthreads();   // barrier A: pmax ready

        float alphaR[4];
#pragma unroll
        for (int r = 0; r < 4; r++) {
            const float m_tile = fmaxf(pmax[w][quad*4 + r], pmax[w ^ 2][quad*4 + r]);
            const float m_new = fmaxf(m_run[r], m_tile);
            alphaR[r] = __expf(m_run[r] - m_new);
            m_run[r] = m_new;
        }
        // P = exp(S - m), accumulate l, write bf16 P
#pragma unroll
        for (int r = 0; r < 4; r++) {
            const float p0 = __expf(sacc[0][r] - m_run[r]);
            const float p1 = __expf(sacc[1][r] - m_run[r]);
            float ps = p0 + p1;
            ps += __shfl_xor(ps, 1);
            ps += __shfl_xor(ps, 2);
            ps += __shfl_xor(ps, 4);
            ps += __shfl_xor(ps, 8);
            l_run[r] = l_run[r] * alphaR[r] + ps;
            const int row = g*16 + quad*4 + r;
            P[row*72 + jh*32 + ln]      = f2bf(p0);
            P[row*72 + jh*32 + 16 + ln] = f2bf(p1);
        }
        if (w < 2 && ln == 0) {
#pragma unroll
            for (int r = 0; r < 4; r++) alpha_lds[g*16 + quad*4 + r] = alphaR[r];
        }
        __syncthreads();   // barrier B: P + alpha ready

        // ---- PV phase ----
        const float a0 = alpha_lds[l32];
#pragma unroll
        for (int rg = 0; rg < 16; rg++) { O0[rg] *= a0; O1[rg] *= a0; }
#pragma unroll
        for (int s = 0; s < 4; s++) {
            const short8 Bf = *(const short8*)&P[l32*72 + s*16 + h32*8];
            const short8 A0 = *(const short8*)(vbase + (size_t)(w*64 + l32)*N_ + jt*64 + s*16 + h32*8);
            const short8 A1 = *(const short8*)(vbase + (size_t)(w*64 + 32 + l32)*N_ + jt*64 + s*16 + h32*8);
            O0 = MFMA32(A0, Bf, O0);
            O1 = MFMA32(A1, Bf, O1);
        }
    }

    // ---- epilogue: combine l across pair waves, scale, add residual ----
    __syncthreads();
    if (ln == 0) {
#pragma unroll
        for (int r = 0; r < 4; r++) lpart[w][quad*4 + r] = l_run[r];
    }
    __syncthreads();
    const int gl = l32 >> 4, li = l32 & 15;
    const float ltot = lpart[gl][li] + lpart[gl + 2][li];
    const float sc = gptr[0] / ltot;
    const int pix = i0 + l32;
#pragma unroll
    for (int mt = 0; mt < 2; mt++) {
        const f32x16 Ot = mt ? O1 : O0;
#pragma unroll
        for (int reg = 0; reg < 16; reg++) {
            const int c = w*64 + mt*32 + (reg & 3) + 8*(reg >> 2) + 4*h32;
            const size_t idx = (size_t)(b*C_ + c)*N_ + pix;
            out[idx] = fmaf(sc, Ot[reg], x[idx]);
        }
    }
}

// ---------------------------------------------------------------------------
extern "C" void kernel_launch(void* const* d_in, const int* in_sizes, int n_in,
                              void* d_out, int out_size, void* d_ws, size_t ws_size,
                              hipStream_t stream)
{
    (void)in_sizes; (void)n_in; (void)out_size; (void)ws_size;
    const float* x  = (const float*)d_in[0];
    const float* wq = (const float*)d_in[1];
    const float* bq = (const float*)d_in[2];
    const float* wk = (const float*)d_in[3];
    const float* bk = (const float*)d_in[4];
    const float* wv = (const float*)d_in[5];
    const float* bv = (const float*)d_in[6];
    const float* gm = (const float*)d_in[7];
    float* out = (float*)d_out;

    unsigned short* u = (unsigned short*)d_ws;
    unsigned short* xhi = u;
    unsigned short* xlo = u + XT_ELEMS;
    unsigned short* Ahi = u + AHI_OFF;
    unsigned short* Alo = u + ALO_OFF;
    unsigned short* qkt_hi = u + QKT_HI_OFF;
    unsigned short* qkt_lo = u + QKT_LO_OFF;
    unsigned short* vbf = u + VBF_OFF;

    hipLaunchKernelGGL(zero_pads, dim3(1024), dim3(256), 0, stream,
                       (uint4*)d_ws, (2*XT_ELEMS*2)/16);
    hipLaunchKernelGGL(prep_x, dim3(4, 56, 8), dim3(256), 0, stream, x, xhi, xlo);
    hipLaunchKernelGGL(prep_w, dim3(2880), dim3(256), 0, stream, wq, wk, wv, Ahi, Alo);
    hipLaunchKernelGGL(conv_qk, dim3(8, 28), dim3(256), 0, stream,
                       xhi, xlo, Ahi, Alo, bq, bk, qkt_hi, qkt_lo);
    hipLaunchKernelGGL(conv_v, dim3(8, 14, 2), dim3(512), 0, stream,
                       xhi, Ahi, bv, vbf);
    hipLaunchKernelGGL(attn_flash, dim3(49*2*8), dim3(256), 0, stream,
                       qkt_hi, qkt_lo, vbf, x, gm, out);
}

// Round 6
// 548.446 us; speedup vs baseline: 1.1143x; 1.1143x over previous
//
#include <hip/hip_runtime.h>
#include <math.h>

// Problem constants
#define B_ 8
#define C_ 256
#define H_ 56
#define W_ 56
#define N_ 3136  // 56*56 = 49*64

typedef __attribute__((ext_vector_type(8))) short short8;
typedef __attribute__((ext_vector_type(4))) float f32x4;
typedef __attribute__((ext_vector_type(16))) float f32x16;
typedef __attribute__((ext_vector_type(4))) unsigned short u16x4;
#define MFMA16(A, Bf, Cf) __builtin_amdgcn_mfma_f32_16x16x32_bf16((A), (Bf), (Cf), 0, 0, 0)
#define MFMA32(A, Bf, Cf) __builtin_amdgcn_mfma_f32_32x32x16_bf16((A), (Bf), (Cf), 0, 0, 0)

// -------------------- workspace layout (ushort units) --------------------
#define XT_ELEMS (B_*58*64*256)           // 7,602,176
#define A_ELEMS  (320*2304)               // 737,280
#define AHI_OFF  (2*XT_ELEMS)
#define ALO_OFF  (AHI_OFF + A_ELEMS)
#define QKT_HI_OFF (ALO_OFF + A_ELEMS)
#define QKT_ELEMS  (B_*N_*64)             // 1,605,632
#define QKT_LO_OFF (QKT_HI_OFF + QKT_ELEMS)
#define VBF_OFF    (QKT_LO_OFF + QKT_ELEMS)
#define VBF_ELEMS  (B_*C_*N_)             // 6,422,528

// LDS swizzle for conv B-slabs: chunk (r,col,c8) -> uint4 index
#define SWZ(r, col, c8) ((((r)*64 + (col))*4) + ((c8) ^ ((col) & 3)))

// P LDS row stride (ushorts): 76*2=152B, 8B-aligned, bank-spread (6 dw mod 32)
#define PSTR 76

__device__ inline unsigned short f2bf(float f) {
    unsigned u = __float_as_uint(f);
    unsigned r = (u + 0x7fffu + ((u >> 16) & 1u)) >> 16;   // RNE
    return (unsigned short)r;
}
__device__ inline float bf2f(unsigned short h) {
    return __uint_as_float(((unsigned)h) << 16);
}

// ---------------------------------------------------------------------------
// Kernel 0: zero the padded x regions.
// ---------------------------------------------------------------------------
__global__ __launch_bounds__(256) void zero_pads(uint4* __restrict__ p, int n16)
{
    const int stride = gridDim.x * 256;
    for (int i = blockIdx.x * 256 + threadIdx.x; i < n16; i += stride)
        p[i] = make_uint4(0, 0, 0, 0);
}

// ---------------------------------------------------------------------------
// Kernel 1a: x (fp32 NCHW) -> padded pixel-major bf16 hi/lo.
// ---------------------------------------------------------------------------
__global__ __launch_bounds__(256) void prep_x(
    const float* __restrict__ x,
    unsigned short* __restrict__ xhi, unsigned short* __restrict__ xlo)
{
    __shared__ float xs[64][57];
    const int cc = blockIdx.x, y = blockIdx.y, b = blockIdx.z;
    const int t = threadIdx.x;
    const int c0 = cc * 64;
    for (int idx = t; idx < 64 * 56; idx += 256) {
        const int ch = idx / 56, xc = idx - ch * 56;
        xs[ch][xc] = x[((size_t)(b*C_ + c0 + ch)*H_ + y)*W_ + xc];
    }
    __syncthreads();
    for (int idx = t; idx < 56 * 32; idx += 256) {
        const int xc = idx >> 5, chp = idx & 31;
        const float v0 = xs[2*chp][xc], v1 = xs[2*chp + 1][xc];
        const unsigned short h0 = f2bf(v0), h1 = f2bf(v1);
        const unsigned short l0 = f2bf(v0 - bf2f(h0));
        const unsigned short l1 = f2bf(v1 - bf2f(h1));
        const size_t o = ((size_t)(b*58 + y + 1) * 64 + (xc + 1)) * 256 + c0 + 2*chp;
        *(unsigned*)(xhi + o) = (unsigned)h0 | ((unsigned)h1 << 16);
        *(unsigned*)(xlo + o) = (unsigned)l0 | ((unsigned)l1 << 16);
    }
}

// ---------------------------------------------------------------------------
// Kernel 1b: weights -> A_hi/A_lo [320][2304], k = s*256 + c.
// ---------------------------------------------------------------------------
__global__ __launch_bounds__(256) void prep_w(
    const float* __restrict__ wq, const float* __restrict__ wk,
    const float* __restrict__ wv,
    unsigned short* __restrict__ Ahi, unsigned short* __restrict__ Alo)
{
    const int g = blockIdx.x * 256 + threadIdx.x;
    if (g >= 320 * 2304) return;
    const int m = g / 2304, k = g - m * 2304;
    const int s = k >> 8, c = k & 255;
    float w;
    if (m < 32)      w = wq[((size_t)m*C_ + c)*9 + s];
    else if (m < 64) w = wk[((size_t)(m-32)*C_ + c)*9 + s];
    else             w = wv[((size_t)(m-64)*C_ + c)*9 + s];
    const unsigned short h = f2bf(w);
    Ahi[g] = h;
    Alo[g] = f2bf(w - bf2f(h));
}

// ---------------------------------------------------------------------------
// Kernel 2a: q/k conv (bf16x3). grid (b 8, yt 28), block 256 = 4 waves.
// ---------------------------------------------------------------------------
__global__ __launch_bounds__(256, 2) void conv_qk(
    const unsigned short* __restrict__ xhi, const unsigned short* __restrict__ xlo,
    const unsigned short* __restrict__ Ahi, const unsigned short* __restrict__ Alo,
    const float* __restrict__ bq, const float* __restrict__ bk,
    unsigned short* __restrict__ qkt_hi, unsigned short* __restrict__ qkt_lo)
{
    __shared__ uint4 sH[4*64*4];   // 16 KB
    __shared__ uint4 sL[4*64*4];   // 16 KB
    const int b = blockIdx.x, yt = blockIdx.y;
    const int y0 = yt * 2;
    const int t = threadIdx.x;
    const int w = t >> 6, L = t & 63;
    const int ln = L & 15, quad = L >> 4;
    const int wm = w & 1, wn = w >> 1;

    f32x4 acc[2][4];
#pragma unroll
    for (int mt = 0; mt < 2; mt++)
#pragma unroll
        for (int nt = 0; nt < 4; nt++) acc[mt][nt] = (f32x4)0.0f;

    uint4 ph[4], pl[4];
#pragma unroll
    for (int i = 0; i < 4; i++) {
        const int idx = t + i*256;
        const int r = idx >> 8, col = (idx >> 2) & 63, c8 = idx & 3;
        const size_t go = ((size_t)((b*58 + y0 + r)*64 + col))*256 + c8*8;
        ph[i] = *(const uint4*)(xhi + go);
        pl[i] = *(const uint4*)(xlo + go);
    }

    for (int cc = 0; cc < 8; cc++) {
        __syncthreads();
#pragma unroll
        for (int i = 0; i < 4; i++) {
            const int idx = t + i*256;
            const int r = idx >> 8, col = (idx >> 2) & 63, c8 = idx & 3;
            sH[SWZ(r, col, c8)] = ph[i];
            sL[SWZ(r, col, c8)] = pl[i];
        }
        __syncthreads();
        if (cc < 7) {
#pragma unroll
            for (int i = 0; i < 4; i++) {
                const int idx = t + i*256;
                const int r = idx >> 8, col = (idx >> 2) & 63, c8 = idx & 3;
                const size_t go = ((size_t)((b*58 + y0 + r)*64 + col))*256 + (cc+1)*32 + c8*8;
                ph[i] = *(const uint4*)(xhi + go);
                pl[i] = *(const uint4*)(xlo + go);
            }
        }
#pragma unroll
        for (int s = 0; s < 9; s++) {
            const int dy = s / 3 - 1, dx = s % 3 - 1;
            short8 ah[2], al[2];
#pragma unroll
            for (int mt = 0; mt < 2; mt++) {
                const size_t off = (size_t)(wm*32 + mt*16 + ln)*2304 + s*256 + cc*32 + quad*8;
                ah[mt] = *(const short8*)(Ahi + off);
                al[mt] = *(const short8*)(Alo + off);
            }
            const int r = wn + dy + 1;
            short8 bh[4], bl[4];
#pragma unroll
            for (int nt = 0; nt < 4; nt++) {
                const int col = nt*16 + ln + dx + 1;
                const int i4 = SWZ(r, col, quad);
                bh[nt] = *(const short8*)&sH[i4];
                bl[nt] = *(const short8*)&sL[i4];
            }
#pragma unroll
            for (int mt = 0; mt < 2; mt++)
#pragma unroll
                for (int nt = 0; nt < 4; nt++) {
                    acc[mt][nt] = MFMA16(ah[mt], bh[nt], acc[mt][nt]);
                    acc[mt][nt] = MFMA16(ah[mt], bl[nt], acc[mt][nt]);
                    acc[mt][nt] = MFMA16(al[mt], bh[nt], acc[mt][nt]);
                }
        }
    }

    const int y = y0 + wn;
#pragma unroll
    for (int nt = 0; nt < 4; nt++) {
        const int px = nt*16 + ln;
        if (px >= 56) continue;
        const int pix = y*56 + px;
#pragma unroll
        for (int mt = 0; mt < 2; mt++) {
            u16x4 hi4, lo4;
#pragma unroll
            for (int r = 0; r < 4; r++) {
                const int m = wm*32 + mt*16 + quad*4 + r;
                const float bias = (m < 32) ? bq[m] : bk[m - 32];
                const float val = acc[mt][nt][r] + bias;
                const unsigned short h = f2bf(val);
                hi4[r] = h;
                lo4[r] = f2bf(val - bf2f(h));
            }
            const size_t o = (size_t)(b*N_ + pix)*64 + wm*32 + mt*16 + quad*4;
            *(u16x4*)(qkt_hi + o) = hi4;
            *(u16x4*)(qkt_lo + o) = lo4;
        }
    }
}

// ---------------------------------------------------------------------------
// Kernel 2b: v conv (plain bf16). grid (b 8, yt 14, mg 2), block 512 = 8 waves.
// ---------------------------------------------------------------------------
__global__ __launch_bounds__(512, 2) void conv_v(
    const unsigned short* __restrict__ xhi,
    const unsigned short* __restrict__ Ahi,
    const float* __restrict__ bv,
    unsigned short* __restrict__ vbf)
{
    __shared__ uint4 sH[6*64*4];   // 24 KB
    const int b = blockIdx.x, yt = blockIdx.y, mg = blockIdx.z;
    const int y0 = yt * 4;
    const int t = threadIdx.x;
    const int w = t >> 6, L = t & 63;
    const int ln = L & 15, quad = L >> 4;
    const int wm = w & 1, wn = w >> 1;
    const int m0 = 64 + mg*128 + wm*64;

    f32x4 acc[4][4];
#pragma unroll
    for (int mt = 0; mt < 4; mt++)
#pragma unroll
        for (int nt = 0; nt < 4; nt++) acc[mt][nt] = (f32x4)0.0f;

    uint4 ph[3];
#pragma unroll
    for (int i = 0; i < 3; i++) {
        const int idx = t + i*512;
        const int r = idx >> 8, col = (idx >> 2) & 63, c8 = idx & 3;
        const size_t go = ((size_t)((b*58 + y0 + r)*64 + col))*256 + c8*8;
        ph[i] = *(const uint4*)(xhi + go);
    }

    for (int cc = 0; cc < 8; cc++) {
        __syncthreads();
#pragma unroll
        for (int i = 0; i < 3; i++) {
            const int idx = t + i*512;
            const int r = idx >> 8, col = (idx >> 2) & 63, c8 = idx & 3;
            sH[SWZ(r, col, c8)] = ph[i];
        }
        __syncthreads();
        if (cc < 7) {
#pragma unroll
            for (int i = 0; i < 3; i++) {
                const int idx = t + i*512;
                const int r = idx >> 8, col = (idx >> 2) & 63, c8 = idx & 3;
                const size_t go = ((size_t)((b*58 + y0 + r)*64 + col))*256 + (cc+1)*32 + c8*8;
                ph[i] = *(const uint4*)(xhi + go);
            }
        }
#pragma unroll
        for (int s = 0; s < 9; s++) {
            const int dy = s / 3 - 1, dx = s % 3 - 1;
            short8 a[4];
#pragma unroll
            for (int mt = 0; mt < 4; mt++) {
                const size_t off = (size_t)(m0 + mt*16 + ln)*2304 + s*256 + cc*32 + quad*8;
                a[mt] = *(const short8*)(Ahi + off);
            }
            const int r = wn + dy + 1;
            short8 bf[4];
#pragma unroll
            for (int nt = 0; nt < 4; nt++) {
                const int col = nt*16 + ln + dx + 1;
                bf[nt] = *(const short8*)&sH[SWZ(r, col, quad)];
            }
#pragma unroll
            for (int mt = 0; mt < 4; mt++)
#pragma unroll
                for (int nt = 0; nt < 4; nt++)
                    acc[mt][nt] = MFMA16(a[mt], bf[nt], acc[mt][nt]);
        }
    }

    const int y = y0 + wn;
#pragma unroll
    for (int nt = 0; nt < 4; nt++) {
        const int px = nt*16 + ln;
        if (px >= 56) continue;
        const int pix = y*56 + px;
#pragma unroll
        for (int mt = 0; mt < 4; mt++) {
#pragma unroll
            for (int r = 0; r < 4; r++) {
                const int c = mg*128 + wm*64 + mt*16 + quad*4 + r;
                vbf[(size_t)(b*C_ + c)*N_ + pix] = f2bf(acc[mt][nt][r] + bv[c]);
            }
        }
    }
}

// ---------------------------------------------------------------------------
// Kernel 3: fused flash attention, v2 (S^T layout, wave-local stats).
// grid (392 = it 49 x b 8, chalf 2), block 256 = 4 waves.
// Block covers i-tile of 64 and c-half of 128. Wave w: S^T for i-rows
// [it*64 + w*16, +16) over ALL 64 j (A=K, B=Q -> per-lane stats, 2 shuffles);
// PV for c-slice w*32 within the half, both 32-i tiles.
// P double-buffered in LDS -> ONE barrier per jt. V prefetched pre-barrier.
// O-rescale ballot-skipped when m did not change.
// ---------------------------------------------------------------------------
__global__ __launch_bounds__(256, 3) void attn_flash2(
    const unsigned short* __restrict__ qkt_hi, const unsigned short* __restrict__ qkt_lo,
    const unsigned short* __restrict__ vbf,
    const float* __restrict__ x, const float* __restrict__ gptr,
    float* __restrict__ out)
{
    __shared__ unsigned short P[2][64*PSTR];   // 19.0 KB
    __shared__ float alphaL[2][64];
    __shared__ float lL[64];

    const int bx = blockIdx.x;
    const int b = bx & 7, it = bx >> 3;
    const int chalf = blockIdx.y;
    const int i_base = it * 64;
    const int t = threadIdx.x;
    const int w = t >> 6, L = t & 63;
    const int ln = L & 15, quad = L >> 4;
    const int l32 = L & 31, h32 = L >> 5;

    // Q B-frags for this wave's 16 i-rows (i = i_base + w*16 + ln)
    const size_t qoff = (size_t)(b*N_ + i_base + w*16 + ln)*64 + quad*8;
    const short8 qh = *(const short8*)(qkt_hi + qoff);
    const short8 ql = *(const short8*)(qkt_lo + qoff);

    float m_run = -INFINITY, l_run = 0.0f;   // per lane, for i = i_base+w*16+ln
    f32x16 O0 = (f32x16)0.0f, O1 = (f32x16)0.0f;
    // V rows: c = chalf*128 + w*32 + l32
    const unsigned short* vrow = vbf + (size_t)(b*C_ + chalf*128 + w*32 + l32) * N_;
    const float* mlnull = nullptr; (void)mlnull;

    for (int jt = 0; jt < 49; jt++) {
        const int buf = jt & 1;
        // ---- S^T phase: D[j_local][i_local], A = K rows, B = Q rows ----
        f32x4 sacc[4];
#pragma unroll
        for (int tj = 0; tj < 4; tj++) {
            const size_t koff = (size_t)(b*N_ + jt*64 + tj*16 + ln)*64 + 32 + quad*8;
            const short8 kh = *(const short8*)(qkt_hi + koff);
            const short8 kl = *(const short8*)(qkt_lo + koff);
            f32x4 a = (f32x4)0.0f;
            a = MFMA16(kh, qh, a);
            a = MFMA16(kh, ql, a);
            a = MFMA16(kl, qh, a);
            sacc[tj] = a;
        }
        // ---- per-lane stats over the 16 in-lane j values + 2 shuffles ----
        float mx = sacc[0][0];
#pragma unroll
        for (int tj = 0; tj < 4; tj++)
#pragma unroll
            for (int r = 0; r < 4; r++) mx = fmaxf(mx, sacc[tj][r]);
        mx = fmaxf(mx, __shfl_xor(mx, 16));
        mx = fmaxf(mx, __shfl_xor(mx, 32));
        const float m_new = fmaxf(m_run, mx);
        const float alpha = __expf(m_run - m_new);
        m_run = m_new;

        float p[4][4];
        float ps = 0.0f;
#pragma unroll
        for (int tj = 0; tj < 4; tj++)
#pragma unroll
            for (int r = 0; r < 4; r++) {
                p[tj][r] = __expf(sacc[tj][r] - m_new);
                ps += p[tj][r];
            }
        ps += __shfl_xor(ps, 16);
        ps += __shfl_xor(ps, 32);
        l_run = l_run * alpha + ps;

        // write P rows i = w*16+ln, j = tj*16 + quad*4 + r (u16x4 stores)
        {
            unsigned short* prow = &P[buf][(w*16 + ln)*PSTR];
#pragma unroll
            for (int tj = 0; tj < 4; tj++) {
                u16x4 pk;
#pragma unroll
                for (int r = 0; r < 4; r++) pk[r] = f2bf(p[tj][r]);
                *(u16x4*)(prow + tj*16 + quad*4) = pk;
            }
        }
        if (quad == 0) alphaL[buf][w*16 + ln] = alpha;

        // ---- V prefetch (independent of P) ----
        short8 Va[4];
#pragma unroll
        for (int s = 0; s < 4; s++)
            Va[s] = *(const short8*)(vrow + jt*64 + s*16 + h32*8);

        __syncthreads();   // the ONE barrier: P[buf] + alphaL[buf] ready

        // ---- PV phase ----
        const float a0 = alphaL[buf][l32];
        const float a1 = alphaL[buf][32 + l32];
        if (__any(a0 != 1.0f || a1 != 1.0f)) {
#pragma unroll
            for (int rg = 0; rg < 16; rg++) { O0[rg] *= a0; O1[rg] *= a1; }
        }
#pragma unroll
        for (int s = 0; s < 4; s++) {
            const short8 B0 = *(const short8*)&P[buf][l32*PSTR + s*16 + h32*8];
            const short8 B1 = *(const short8*)&P[buf][(32 + l32)*PSTR + s*16 + h32*8];
            O0 = MFMA32(Va[s], B0, O0);
            O1 = MFMA32(Va[s], B1, O1);
        }
    }

    // ---- epilogue ----
    __syncthreads();
    if (quad == 0) lL[w*16 + ln] = l_run;
    __syncthreads();
    const float gamma = gptr[0];
    const float sc0 = gamma / lL[l32];
    const float sc1 = gamma / lL[32 + l32];
#pragma unroll
    for (int itile = 0; itile < 2; itile++) {
        const f32x16 Ot = itile ? O1 : O0;
        const float sc = itile ? sc1 : sc0;
        const int pix = i_base + itile*32 + l32;
#pragma unroll
        for (int reg = 0; reg < 16; reg++) {
            const int c = chalf*128 + w*32 + (reg & 3) + 8*(reg >> 2) + 4*h32;
            const size_t idx = (size_t)(b*C_ + c)*N_ + pix;
            out[idx] = fmaf(sc, Ot[reg], x[idx]);
        }
    }
}

// ---------------------------------------------------------------------------
extern "C" void kernel_launch(void* const* d_in, const int* in_sizes, int n_in,
                              void* d_out, int out_size, void* d_ws, size_t ws_size,
                              hipStream_t stream)
{
    (void)in_sizes; (void)n_in; (void)out_size; (void)ws_size;
    const float* x  = (const float*)d_in[0];
    const float* wq = (const float*)d_in[1];
    const float* bq = (const float*)d_in[2];
    const float* wk = (const float*)d_in[3];
    const float* bk = (const float*)d_in[4];
    const float* wv = (const float*)d_in[5];
    const float* bv = (const float*)d_in[6];
    const float* gm = (const float*)d_in[7];
    float* out = (float*)d_out;

    unsigned short* u = (unsigned short*)d_ws;
    unsigned short* xhi = u;
    unsigned short* xlo = u + XT_ELEMS;
    unsigned short* Ahi = u + AHI_OFF;
    unsigned short* Alo = u + ALO_OFF;
    unsigned short* qkt_hi = u + QKT_HI_OFF;
    unsigned short* qkt_lo = u + QKT_LO_OFF;
    unsigned short* vbf = u + VBF_OFF;

    hipLaunchKernelGGL(zero_pads, dim3(1024), dim3(256), 0, stream,
                       (uint4*)d_ws, (2*XT_ELEMS*2)/16);
    hipLaunchKernelGGL(prep_x, dim3(4, 56, 8), dim3(256), 0, stream, x, xhi, xlo);
    hipLaunchKernelGGL(prep_w, dim3(2880), dim3(256), 0, stream, wq, wk, wv, Ahi, Alo);
    hipLaunchKernelGGL(conv_qk, dim3(8, 28), dim3(256), 0, stream,
                       xhi, xlo, Ahi, Alo, bq, bk, qkt_hi, qkt_lo);
    hipLaunchKernelGGL(conv_v, dim3(8, 14, 2), dim3(512), 0, stream,
                       xhi, Ahi, bv, vbf);
    hipLaunchKernelGGL(attn_flash2, dim3(49*8, 2), dim3(256), 0, stream,
                       qkt_hi, qkt_lo, vbf, x, gm, out);
}